// Round 2
// baseline (906.226 us; speedup 1.0000x reference)
//
#include <hip/hip_runtime.h>
#include <hip/hip_bf16.h>

typedef __attribute__((ext_vector_type(8))) short short8;
typedef __attribute__((ext_vector_type(4))) float floatx4;
typedef __attribute__((ext_vector_type(4))) unsigned short ushort4_t;

#define B_    8
#define S_    8192
#define D_    512
#define E_    16
#define DFF_  512
#define KROW_ 1024   // tokens per expert (capacity)

__device__ __forceinline__ float bf2f(unsigned short u) {
    return __uint_as_float(((unsigned int)u) << 16);
}
__device__ __forceinline__ unsigned short f2bf(float f) {
    unsigned int u = __float_as_uint(f);
    u += 0x7FFFu + ((u >> 16) & 1u);
    return (unsigned short)(u >> 16);
}
__device__ __forceinline__ float gelu_tanh(float v) {
    // jax.nn.gelu default: approximate=True (tanh form)
    return 0.5f * v * (1.f + tanhf(0.7978845608028654f * (v + 0.044715f * v * v * v)));
}

#define GLD16(g, l) __builtin_amdgcn_global_load_lds( \
    (const __attribute__((address_space(1))) void*)(g), \
    (__attribute__((address_space(3))) void*)(l), 16, 0, 0)

// ---------------------------------------------------------------------------
// x fp32 -> xb bf16 (flat, coalesced)
// ---------------------------------------------------------------------------
__global__ __launch_bounds__(256) void cvt_x_k(
    const float* __restrict__ x, unsigned short* __restrict__ xb, int n4)
{
    int i = blockIdx.x * 256 + threadIdx.x;
    if (i >= n4) return;
    float4 v = ((const float4*)x)[i];
    ushort4_t o;
    o[0] = f2bf(v.x); o[1] = f2bf(v.y); o[2] = f2bf(v.z); o[3] = f2bf(v.w);
    ((ushort4_t*)xb)[i] = o;
}

// ---------------------------------------------------------------------------
// w1[e][D][DFF] fp32 -> w1t[e][DFF][D] bf16 ; w2[e][DFF][D] fp32 -> w2t[e][D][DFF] bf16
// (both 512x512 per expert). blockIdx.z<16 -> w1, else w2.
// ---------------------------------------------------------------------------
__global__ __launch_bounds__(256) void transpose_w_k(
    const float* __restrict__ w1, const float* __restrict__ w2,
    unsigned short* __restrict__ w1t, unsigned short* __restrict__ w2t)
{
    __shared__ unsigned short tile[32][33];
    const int e = blockIdx.z & 15;
    const float*    src = (blockIdx.z < 16) ? w1 : w2;
    unsigned short* dst = (blockIdx.z < 16) ? w1t : w2t;
    const int x0 = blockIdx.x * 32, y0 = blockIdx.y * 32;
    const int tx = threadIdx.x, ty = threadIdx.y;   // block (32,8)
    const size_t base = (size_t)e * 512 * 512;
#pragma unroll
    for (int i = 0; i < 4; ++i)
        tile[ty + 8 * i][tx] = f2bf(src[base + (size_t)(y0 + ty + 8 * i) * 512 + x0 + tx]);
    __syncthreads();
#pragma unroll
    for (int i = 0; i < 4; ++i)
        dst[base + (size_t)(x0 + ty + 8 * i) * 512 + y0 + tx] = tile[tx][ty + 8 * i];
}

// ---------------------------------------------------------------------------
// Router (all fp32): logits = x @ gw, softmax over E=16, aff[B][E][S].
// One thread per token; gw (32 KB) staged in LDS, broadcast reads.
// ---------------------------------------------------------------------------
__global__ __launch_bounds__(256) void router_k(
    const float* __restrict__ x,   // [B,S,D]
    const float* __restrict__ gw,  // [D,E]
    float* __restrict__ aff)       // [B,E,S]
{
    __shared__ float gws[D_ * E_];
    const int t = threadIdx.x;
    for (int i = t; i < D_ * E_; i += 256) gws[i] = gw[i];
    __syncthreads();

    const int tok = blockIdx.x * 256 + t;
    const float4* xr = (const float4*)(x + (size_t)tok * D_);
    float acc[E_];
#pragma unroll
    for (int e = 0; e < E_; ++e) acc[e] = 0.f;

    for (int d4 = 0; d4 < D_ / 4; ++d4) {
        float4 v = xr[d4];
#pragma unroll
        for (int q = 0; q < 4; ++q) {
            const float xv = (&v.x)[q];
            const float* g = &gws[(d4 * 4 + q) * E_];   // wave-uniform -> LDS broadcast
#pragma unroll
            for (int e = 0; e < E_; ++e) acc[e] = fmaf(xv, g[e], acc[e]);
        }
    }
    float mx = acc[0];
#pragma unroll
    for (int e = 1; e < E_; ++e) mx = fmaxf(mx, acc[e]);
    float sm = 0.f;
#pragma unroll
    for (int e = 0; e < E_; ++e) { acc[e] = expf(acc[e] - mx); sm += acc[e]; }
    const float inv = 1.f / sm;
    const int b = tok >> 13, s = tok & (S_ - 1);
#pragma unroll
    for (int e = 0; e < E_; ++e)
        aff[((size_t)b * E_ + e) * S_ + s] = acc[e] * inv;   // coalesced per e
}

// ---------------------------------------------------------------------------
// Top-k per (b,e): exact k-th-largest via bit-pattern bisection, stable ties.
// Writes idx[b,e,slot]=s and map[b,s,e]=slot (map pre-set to -1).
// Keys are positive fp32 -> unsigned bit compare == float compare.
// ---------------------------------------------------------------------------
__global__ __launch_bounds__(256) void topk_k(
    const float* __restrict__ aff, int* __restrict__ idxb, int* __restrict__ map)
{
    __shared__ unsigned int keys[S_];
    __shared__ int red[4];
    __shared__ unsigned int ctr;
    const int b = blockIdx.x >> 4, e = blockIdx.x & 15;
    const float* a = aff + ((size_t)b * E_ + e) * S_;
    const int t = threadIdx.x;

    for (int i = t; i < S_; i += 256) keys[i] = __float_as_uint(a[i]);
    if (t == 0) ctr = 0;
    __syncthreads();

    unsigned int lo = 0, hi = 0x7F800000u;
    while (lo < hi) {
        unsigned int mid = lo + ((hi - lo + 1) >> 1);
        int cnt = 0;
        for (int i = t; i < S_; i += 256) cnt += (keys[i] >= mid);
#pragma unroll
        for (int o = 32; o > 0; o >>= 1) cnt += __shfl_down(cnt, o);
        if ((t & 63) == 0) red[t >> 6] = cnt;
        __syncthreads();
        int total = red[0] + red[1] + red[2] + red[3];
        __syncthreads();
        if (total >= KROW_) lo = mid; else hi = mid - 1;
    }
    int cg = 0;
    for (int i = t; i < S_; i += 256) cg += (keys[i] > lo);
#pragma unroll
    for (int o = 32; o > 0; o >>= 1) cg += __shfl_down(cg, o);
    if ((t & 63) == 0) red[t >> 6] = cg;
    __syncthreads();
    const int m_gt = red[0] + red[1] + red[2] + red[3];
    const int need_eq = KROW_ - m_gt;
    __syncthreads();

    int* idxg = idxb + ((size_t)b * E_ + e) * KROW_;
    for (int i = t; i < S_; i += 256) {
        unsigned int kv = keys[i];
        if (kv > lo) {
            int slot = (int)atomicAdd(&ctr, 1u);
            idxg[slot] = i;
            map[((size_t)b * S_ + i) * E_ + e] = slot;
        } else if (kv == lo) {
            int rank = 0;
            for (int j = 0; j < i; ++j) rank += (keys[j] == lo);  // ties are rare
            if (rank < need_eq) {
                idxg[m_gt + rank] = i;
                map[((size_t)b * S_ + i) * E_ + e] = m_gt + rank;
            }
        }
    }
}

// ---------------------------------------------------------------------------
// GEMM1: h[bl,e,j,:] = gelu( xb[b, idx[b,e,j], :] @ w1t[e]^T + b1[e] )
// 128x128 tile, BK=32, global_load_lds(16B), mfma 16x16x32 bf16.
// ---------------------------------------------------------------------------
__global__ __launch_bounds__(256) void gemm1_k(
    const unsigned short* __restrict__ xb,   // [B,S,D] bf16
    const unsigned short* __restrict__ w1t,  // [E,DFF,D] bf16 (B^T: [N,K])
    const float* __restrict__ b1,            // [E,DFF] fp32
    const int* __restrict__ idxb,            // [B,E,KROW]
    unsigned short* __restrict__ h,          // [bchunk,E,KROW,DFF] bf16
    int b_base)
{
    __shared__ unsigned short As[128 * 32];
    __shared__ unsigned short Bs[128 * 32];
    const int e  = blockIdx.z & 15;
    const int bl = blockIdx.z >> 4;
    const int b  = b_base + bl;
    const int m0 = blockIdx.x * 128;
    const int n0 = blockIdx.y * 128;
    const int t = threadIdx.x;
    const int w = t >> 6, l = t & 63;
    const int r0 = t >> 2, c0 = (t & 3) * 8;

    const int* idxg = idxb + ((size_t)b * E_ + e) * KROW_;
    const int s0 = idxg[m0 + r0];
    const int s1 = idxg[m0 + 64 + r0];
    const unsigned short* a0 = xb + ((size_t)b * S_ + s0) * D_ + c0;
    const unsigned short* a1 = xb + ((size_t)b * S_ + s1) * D_ + c0;
    const unsigned short* g0 = w1t + ((size_t)e * DFF_ + n0 + r0) * D_ + c0;
    const unsigned short* g1 = w1t + ((size_t)e * DFF_ + n0 + 64 + r0) * D_ + c0;
    unsigned short* asd = &As[w * 512];   // wave-uniform LDS base (+ lane*16B implicit)
    unsigned short* bsd = &Bs[w * 512];

    floatx4 acc[4][4];
#pragma unroll
    for (int i = 0; i < 4; ++i)
#pragma unroll
        for (int j = 0; j < 4; ++j) acc[i][j] = (floatx4){0.f, 0.f, 0.f, 0.f};

    const int wm = (w >> 1) * 64, wn = (w & 1) * 64;
    const int lane15 = l & 15, lk = (l >> 4) * 8;

    for (int k0 = 0; k0 < D_; k0 += 32) {
        __syncthreads();
        GLD16(a0 + k0, asd);
        GLD16(a1 + k0, asd + 2048);
        GLD16(g0 + k0, bsd);
        GLD16(g1 + k0, bsd + 2048);
        __syncthreads();
        short8 af[4], bf[4];
#pragma unroll
        for (int i = 0; i < 4; ++i) af[i] = *(const short8*)&As[(wm + i * 16 + lane15) * 32 + lk];
#pragma unroll
        for (int j = 0; j < 4; ++j) bf[j] = *(const short8*)&Bs[(wn + j * 16 + lane15) * 32 + lk];
#pragma unroll
        for (int i = 0; i < 4; ++i)
#pragma unroll
            for (int j = 0; j < 4; ++j)
                acc[i][j] = __builtin_amdgcn_mfma_f32_16x16x32_bf16(af[i], bf[j], acc[i][j], 0, 0, 0);
    }

    const size_t hbase = ((size_t)bl * E_ + e) * KROW_ * DFF_;
#pragma unroll
    for (int i = 0; i < 4; ++i)
#pragma unroll
        for (int j = 0; j < 4; ++j) {
            const int n = n0 + wn + j * 16 + lane15;
            const float bias = b1[e * DFF_ + n];
#pragma unroll
            for (int r = 0; r < 4; ++r) {
                const int m = m0 + wm + i * 16 + (l >> 4) * 4 + r;
                h[hbase + (size_t)m * DFF_ + n] = f2bf(gelu_tanh(acc[i][j][r] + bias));
            }
        }
}

// ---------------------------------------------------------------------------
// GEMM2: ex[bl,e,j,:] = h[bl,e,j,:] @ w2t[e]^T + b2[e]
// ---------------------------------------------------------------------------
__global__ __launch_bounds__(256) void gemm2_k(
    const unsigned short* __restrict__ h,    // [bchunk,E,KROW,DFF] bf16
    const unsigned short* __restrict__ w2t,  // [E,D,DFF] bf16 (B^T: [N,K])
    const float* __restrict__ b2,            // [E,D] fp32
    unsigned short* __restrict__ ex)         // [bchunk,E,KROW,D] bf16
{
    __shared__ unsigned short As[128 * 32];
    __shared__ unsigned short Bs[128 * 32];
    const int e  = blockIdx.z & 15;
    const int bl = blockIdx.z >> 4;
    const int m0 = blockIdx.x * 128;
    const int n0 = blockIdx.y * 128;
    const int t = threadIdx.x;
    const int w = t >> 6, l = t & 63;
    const int r0 = t >> 2, c0 = (t & 3) * 8;

    const unsigned short* a0 = h + (((size_t)bl * E_ + e) * KROW_ + m0 + r0) * DFF_ + c0;
    const unsigned short* a1 = h + (((size_t)bl * E_ + e) * KROW_ + m0 + 64 + r0) * DFF_ + c0;
    const unsigned short* g0 = w2t + ((size_t)e * D_ + n0 + r0) * DFF_ + c0;
    const unsigned short* g1 = w2t + ((size_t)e * D_ + n0 + 64 + r0) * DFF_ + c0;
    unsigned short* asd = &As[w * 512];
    unsigned short* bsd = &Bs[w * 512];

    floatx4 acc[4][4];
#pragma unroll
    for (int i = 0; i < 4; ++i)
#pragma unroll
        for (int j = 0; j < 4; ++j) acc[i][j] = (floatx4){0.f, 0.f, 0.f, 0.f};

    const int wm = (w >> 1) * 64, wn = (w & 1) * 64;
    const int lane15 = l & 15, lk = (l >> 4) * 8;

    for (int k0 = 0; k0 < DFF_; k0 += 32) {
        __syncthreads();
        GLD16(a0 + k0, asd);
        GLD16(a1 + k0, asd + 2048);
        GLD16(g0 + k0, bsd);
        GLD16(g1 + k0, bsd + 2048);
        __syncthreads();
        short8 af[4], bf[4];
#pragma unroll
        for (int i = 0; i < 4; ++i) af[i] = *(const short8*)&As[(wm + i * 16 + lane15) * 32 + lk];
#pragma unroll
        for (int j = 0; j < 4; ++j) bf[j] = *(const short8*)&Bs[(wn + j * 16 + lane15) * 32 + lk];
#pragma unroll
        for (int i = 0; i < 4; ++i)
#pragma unroll
            for (int j = 0; j < 4; ++j)
                acc[i][j] = __builtin_amdgcn_mfma_f32_16x16x32_bf16(af[i], bf[j], acc[i][j], 0, 0, 0);
    }

    const size_t xbase = ((size_t)bl * E_ + e) * KROW_ * D_;
#pragma unroll
    for (int i = 0; i < 4; ++i)
#pragma unroll
        for (int j = 0; j < 4; ++j) {
            const int n = n0 + wn + j * 16 + lane15;
            const float bias = b2[e * D_ + n];
#pragma unroll
            for (int r = 0; r < 4; ++r) {
                const int m = m0 + wm + i * 16 + (l >> 4) * 4 + r;
                ex[xbase + (size_t)m * D_ + n] = f2bf(acc[i][j][r] + bias);
            }
        }
}

// ---------------------------------------------------------------------------
// Combine: out[b,s,:] = sum_e aff[b,e,s] * ex[bl,e,map[b,s,e],:]   (fp32 out)
// One wave per token; lanes 0..15 fetch map+gate; 16B vector loads, 32B stores.
// ---------------------------------------------------------------------------
__global__ __launch_bounds__(256) void combine_k(
    const unsigned short* __restrict__ ex, const float* __restrict__ aff,
    const int* __restrict__ map, float* __restrict__ out, int b_base)
{
    const int t = threadIdx.x;
    const int w = t >> 6, l = t & 63;
    const size_t tokl = (size_t)blockIdx.x * 4 + w;   // local token within chunk
    const int bl = (int)(tokl >> 13);
    const int s  = (int)(tokl & (S_ - 1));
    const int b  = b_base + bl;

    int jv = -1; float gv = 0.f;
    if (l < 16) {
        jv = map[((size_t)b * S_ + s) * E_ + l];
        gv = aff[((size_t)b * E_ + l) * S_ + s];
    }
    float acc[8] = {0.f, 0.f, 0.f, 0.f, 0.f, 0.f, 0.f, 0.f};
#pragma unroll
    for (int e = 0; e < E_; ++e) {
        const int je = __shfl(jv, e);
        if (je < 0) continue;
        const float ge = __shfl(gv, e);
        const unsigned short* row = ex + (((size_t)bl * E_ + e) * KROW_ + je) * D_ + l * 8;
        short8 v = *(const short8*)row;
#pragma unroll
        for (int q = 0; q < 8; ++q) acc[q] += ge * bf2f((unsigned short)v[q]);
    }
    float* orow = out + ((size_t)b * S_ + s) * D_ + l * 8;
    float4 o0 = {acc[0], acc[1], acc[2], acc[3]};
    float4 o1 = {acc[4], acc[5], acc[6], acc[7]};
    ((float4*)orow)[0] = o0;
    ((float4*)orow)[1] = o1;
}

// ---------------------------------------------------------------------------
extern "C" void kernel_launch(void* const* d_in, const int* in_sizes, int n_in,
                              void* d_out, int out_size, void* d_ws, size_t ws_size,
                              hipStream_t stream) {
    const float* x  = (const float*)d_in[0];
    const float* gw = (const float*)d_in[1];
    const float* w1 = (const float*)d_in[2];
    const float* b1 = (const float*)d_in[3];
    const float* w2 = (const float*)d_in[4];
    const float* b2 = (const float*)d_in[5];
    float* out = (float*)d_out;
    char* ws = (char*)d_ws;

    size_t off = 0;
    float* aff = (float*)(ws + off);          off += (size_t)B_ * E_ * S_ * 4;       // 4 MB
    int* idxb  = (int*)(ws + off);            off += (size_t)B_ * E_ * KROW_ * 4;    // 0.5 MB
    int* map   = (int*)(ws + off);            off += (size_t)B_ * S_ * E_ * 4;       // 4 MB
    unsigned short* w1t = (unsigned short*)(ws + off); off += (size_t)E_ * DFF_ * D_ * 2; // 8 MB
    unsigned short* w2t = (unsigned short*)(ws + off); off += (size_t)E_ * D_ * DFF_ * 2; // 8 MB
    unsigned short* xb  = (unsigned short*)(ws + off); off += (size_t)B_ * S_ * D_ * 2;   // 64 MB
    const size_t fixed = off;
    const size_t per_b_h  = (size_t)E_ * KROW_ * DFF_ * 2;   // 16 MB
    const size_t per_b_ex = (size_t)E_ * KROW_ * D_ * 2;     // 16 MB
    const size_t per_b = per_b_h + per_b_ex;

    int bchunk = 1;
    if (ws_size > fixed + per_b) {
        size_t m = (ws_size - fixed) / per_b;
        bchunk = (int)(m > (size_t)B_ ? (size_t)B_ : m);
        if (bchunk < 1) bchunk = 1;
    }
    unsigned short* h  = (unsigned short*)(ws + fixed);
    unsigned short* ex = (unsigned short*)(ws + fixed + (size_t)bchunk * per_b_h);

    hipMemsetAsync(map, 0xFF, (size_t)B_ * S_ * E_ * 4, stream);
    cvt_x_k<<<dim3((B_ * S_ * D_ / 4 + 255) / 256), dim3(256), 0, stream>>>(
        x, xb, B_ * S_ * D_ / 4);
    transpose_w_k<<<dim3(16, 16, 32), dim3(32, 8, 1), 0, stream>>>(w1, w2, w1t, w2t);
    router_k<<<dim3((B_ * S_) / 256), dim3(256), 0, stream>>>(x, gw, aff);
    topk_k<<<dim3(B_ * E_), dim3(256), 0, stream>>>(aff, idxb, map);

    for (int b0 = 0; b0 < B_; b0 += bchunk) {
        const int bc = (b0 + bchunk <= B_) ? bchunk : (B_ - b0);
        gemm1_k<<<dim3(KROW_ / 128, DFF_ / 128, bc * E_), dim3(256), 0, stream>>>(
            xb, w1t, b1, idxb, h, b0);
        gemm2_k<<<dim3(KROW_ / 128, D_ / 128, bc * E_), dim3(256), 0, stream>>>(
            h, w2t, b2, ex);
        combine_k<<<dim3(bc * (S_ / 4)), dim3(256), 0, stream>>>(ex, aff, map, out, b0);
    }
}

// Round 3
// 631.810 us; speedup vs baseline: 1.4343x; 1.4343x over previous
//
#include <hip/hip_runtime.h>
#include <hip/hip_bf16.h>

typedef __attribute__((ext_vector_type(8))) short short8;
typedef __attribute__((ext_vector_type(4))) float floatx4;
typedef __attribute__((ext_vector_type(4))) unsigned short ushort4_t;

#define B_    8
#define S_    8192
#define D_    512
#define E_    16
#define DFF_  512
#define KROW_ 1024   // tokens per expert (capacity)

__device__ __forceinline__ float bf2f(unsigned short u) {
    return __uint_as_float(((unsigned int)u) << 16);
}
__device__ __forceinline__ unsigned short f2bf(float f) {
    unsigned int u = __float_as_uint(f);
    u += 0x7FFFu + ((u >> 16) & 1u);
    return (unsigned short)(u >> 16);
}
__device__ __forceinline__ float gelu_tanh(float v) {
    // jax.nn.gelu default: approximate=True (tanh form)
    return 0.5f * v * (1.f + tanhf(0.7978845608028654f * (v + 0.044715f * v * v * v)));
}

#define GLD16(g, l) __builtin_amdgcn_global_load_lds( \
    (const __attribute__((address_space(1))) void*)(g), \
    (__attribute__((address_space(3))) void*)(l), 16, 0, 0)

// ---------------------------------------------------------------------------
// x fp32 -> xb bf16 (flat, coalesced)
// ---------------------------------------------------------------------------
__global__ __launch_bounds__(256) void cvt_x_k(
    const float* __restrict__ x, unsigned short* __restrict__ xb, int n4)
{
    int i = blockIdx.x * 256 + threadIdx.x;
    if (i >= n4) return;
    float4 v = ((const float4*)x)[i];
    ushort4_t o;
    o[0] = f2bf(v.x); o[1] = f2bf(v.y); o[2] = f2bf(v.z); o[3] = f2bf(v.w);
    ((ushort4_t*)xb)[i] = o;
}

// ---------------------------------------------------------------------------
// w1[e][D][DFF] fp32 -> w1t[e][DFF][D] bf16 ; w2[e][DFF][D] fp32 -> w2t[e][D][DFF] bf16
// ---------------------------------------------------------------------------
__global__ __launch_bounds__(256) void transpose_w_k(
    const float* __restrict__ w1, const float* __restrict__ w2,
    unsigned short* __restrict__ w1t, unsigned short* __restrict__ w2t)
{
    __shared__ unsigned short tile[32][33];
    const int e = blockIdx.z & 15;
    const float*    src = (blockIdx.z < 16) ? w1 : w2;
    unsigned short* dst = (blockIdx.z < 16) ? w1t : w2t;
    const int x0 = blockIdx.x * 32, y0 = blockIdx.y * 32;
    const int tx = threadIdx.x, ty = threadIdx.y;   // block (32,8)
    const size_t base = (size_t)e * 512 * 512;
#pragma unroll
    for (int i = 0; i < 4; ++i)
        tile[ty + 8 * i][tx] = f2bf(src[base + (size_t)(y0 + ty + 8 * i) * 512 + x0 + tx]);
    __syncthreads();
#pragma unroll
    for (int i = 0; i < 4; ++i)
        dst[base + (size_t)(x0 + ty + 8 * i) * 512 + y0 + tx] = tile[tx][ty + 8 * i];
}

// ---------------------------------------------------------------------------
// Router (all fp32): logits = x @ gw, softmax over E=16, aff[B][E][S].
// ---------------------------------------------------------------------------
__global__ __launch_bounds__(256) void router_k(
    const float* __restrict__ x,   // [B,S,D]
    const float* __restrict__ gw,  // [D,E]
    float* __restrict__ aff)       // [B,E,S]
{
    __shared__ float gws[D_ * E_];
    const int t = threadIdx.x;
    for (int i = t; i < D_ * E_; i += 256) gws[i] = gw[i];
    __syncthreads();

    const int tok = blockIdx.x * 256 + t;
    const float4* xr = (const float4*)(x + (size_t)tok * D_);
    float acc[E_];
#pragma unroll
    for (int e = 0; e < E_; ++e) acc[e] = 0.f;

    for (int d4 = 0; d4 < D_ / 4; ++d4) {
        float4 v = xr[d4];
#pragma unroll
        for (int q = 0; q < 4; ++q) {
            const float xv = (&v.x)[q];
            const float* g = &gws[(d4 * 4 + q) * E_];   // wave-uniform -> LDS broadcast
#pragma unroll
            for (int e = 0; e < E_; ++e) acc[e] = fmaf(xv, g[e], acc[e]);
        }
    }
    float mx = acc[0];
#pragma unroll
    for (int e = 1; e < E_; ++e) mx = fmaxf(mx, acc[e]);
    float sm = 0.f;
#pragma unroll
    for (int e = 0; e < E_; ++e) { acc[e] = expf(acc[e] - mx); sm += acc[e]; }
    const float inv = 1.f / sm;
    const int b = tok >> 13, s = tok & (S_ - 1);
#pragma unroll
    for (int e = 0; e < E_; ++e)
        aff[((size_t)b * E_ + e) * S_ + s] = acc[e] * inv;   // coalesced per e
}

// ---------------------------------------------------------------------------
// Top-k per (b,e): exact k-th-largest via 4-level MSB radix select (8/8/8/7
// bits), stable ties by ascending index. 1024 threads, keys LDS-resident.
// Keys are positive fp32 -> unsigned bit compare == float compare.
// Writes idx[b,e,slot]=s and map[b,s,e]=slot (map pre-set to -1).
// ---------------------------------------------------------------------------
__global__ __launch_bounds__(1024) void topk_k(
    const float* __restrict__ aff, int* __restrict__ idxb, int* __restrict__ map)
{
    __shared__ unsigned int keys[S_];        // 32 KB
    __shared__ unsigned int hist[4][257];    // 4 privatized copies, +1 pad (bank spread)
    __shared__ unsigned int sbuf[256];
    __shared__ unsigned int scan[1024];
    __shared__ unsigned int sh_b, sh_above, sh_ctr;

    const int b = blockIdx.x >> 4, e = blockIdx.x & 15;
    const float* a = aff + ((size_t)b * E_ + e) * S_;
    const int t = threadIdx.x;

    for (int i = t; i < S_; i += 1024) keys[i] = __float_as_uint(a[i]);
    if (t == 0) sh_ctr = 0;
    __syncthreads();

    unsigned int prefix = 0, need = KROW_;
#pragma unroll
    for (int lev = 0; lev < 4; ++lev) {
        const int shift = (lev == 0) ? 23 : (lev == 1) ? 15 : (lev == 2) ? 7 : 0;
        const int bins  = (lev == 3) ? 128 : 256;
        const unsigned int fmask = (unsigned int)(bins - 1);
        const int sw = shift + ((lev == 3) ? 7 : 8);
        const unsigned int mask_hi = 0xFFFFFFFFu << sw;

        hist[t >> 8][t & 255] = 0;
        __syncthreads();
        for (int i = t; i < S_; i += 1024) {
            unsigned int k = keys[i];
            if ((k & mask_hi) == prefix)
                atomicAdd(&hist[t >> 8][(k >> shift) & fmask], 1u);
        }
        __syncthreads();
        if (t < 256) sbuf[t] = hist[0][t] + hist[1][t] + hist[2][t] + hist[3][t];
        // inclusive suffix scan over 256 bins (entries >= bins are zero)
        for (int off = 1; off < 256; off <<= 1) {
            __syncthreads();
            unsigned int v = 0;
            if (t < 256 && t + off < 256) v = sbuf[t + off];
            __syncthreads();
            if (t < 256) sbuf[t] += v;
        }
        __syncthreads();
        if (t < bins) {
            unsigned int c  = sbuf[t];
            unsigned int cn = (t + 1 < bins) ? sbuf[t + 1] : 0u;
            if (c >= need && cn < need) { sh_b = (unsigned int)t; sh_above = cn; }
        }
        __syncthreads();
        prefix |= sh_b << shift;
        need   -= sh_above;
        __syncthreads();
    }

    const unsigned int T = prefix;          // exact k-th largest key
    const unsigned int need_eq = need;      // # ties (==T) to keep
    const unsigned int m_gt = KROW_ - need_eq;

    int* idxg = idxb + ((size_t)b * E_ + e) * KROW_;
    for (int i = t; i < S_; i += 1024) {
        unsigned int k = keys[i];
        if (k > T) {
            unsigned int slot = atomicAdd(&sh_ctr, 1u);
            idxg[slot] = i;
            map[((size_t)b * S_ + i) * E_ + e] = (int)slot;
        }
    }
    // stable tie ranking: prefix scan of per-thread tie counts (8 keys/thread)
    unsigned int lt = 0;
    const int i0 = t * 8;
#pragma unroll
    for (int q = 0; q < 8; ++q) lt += (keys[i0 + q] == T);
    scan[t] = lt;
    for (int off = 1; off < 1024; off <<= 1) {
        __syncthreads();
        unsigned int v = (t >= off) ? scan[t - off] : 0u;
        __syncthreads();
        scan[t] += v;
    }
    __syncthreads();
    unsigned int r = scan[t] - lt;          // exclusive prefix
#pragma unroll
    for (int q = 0; q < 8; ++q) {
        if (keys[i0 + q] == T) {
            if (r < need_eq) {
                idxg[m_gt + r] = i0 + q;
                map[((size_t)b * S_ + (i0 + q)) * E_ + e] = (int)(m_gt + r);
            }
            r++;
        }
    }
}

// ---------------------------------------------------------------------------
// GEMM1: h[bl,e,j,:] = gelu( xb[b, idx[b,e,j], :] @ w1t[e]^T + b1[e] )
// 128x128 tile, BK=32, global_load_lds(16B), mfma 16x16x32 bf16.
// ---------------------------------------------------------------------------
__global__ __launch_bounds__(256) void gemm1_k(
    const unsigned short* __restrict__ xb,   // [B,S,D] bf16
    const unsigned short* __restrict__ w1t,  // [E,DFF,D] bf16 (B^T: [N,K])
    const float* __restrict__ b1,            // [E,DFF] fp32
    const int* __restrict__ idxb,            // [B,E,KROW]
    unsigned short* __restrict__ h,          // [bchunk,E,KROW,DFF] bf16
    int b_base)
{
    __shared__ unsigned short As[128 * 32];
    __shared__ unsigned short Bs[128 * 32];
    const int e  = blockIdx.z & 15;
    const int bl = blockIdx.z >> 4;
    const int b  = b_base + bl;
    const int m0 = blockIdx.x * 128;
    const int n0 = blockIdx.y * 128;
    const int t = threadIdx.x;
    const int w = t >> 6, l = t & 63;
    const int r0 = t >> 2, c0 = (t & 3) * 8;

    const int* idxg = idxb + ((size_t)b * E_ + e) * KROW_;
    const int s0 = idxg[m0 + r0];
    const int s1 = idxg[m0 + 64 + r0];
    const unsigned short* a0 = xb + ((size_t)b * S_ + s0) * D_ + c0;
    const unsigned short* a1 = xb + ((size_t)b * S_ + s1) * D_ + c0;
    const unsigned short* g0 = w1t + ((size_t)e * DFF_ + n0 + r0) * D_ + c0;
    const unsigned short* g1 = w1t + ((size_t)e * DFF_ + n0 + 64 + r0) * D_ + c0;
    unsigned short* asd = &As[w * 512];   // wave-uniform LDS base (+ lane*16B implicit)
    unsigned short* bsd = &Bs[w * 512];

    floatx4 acc[4][4];
#pragma unroll
    for (int i = 0; i < 4; ++i)
#pragma unroll
        for (int j = 0; j < 4; ++j) acc[i][j] = (floatx4){0.f, 0.f, 0.f, 0.f};

    const int wm = (w >> 1) * 64, wn = (w & 1) * 64;
    const int lane15 = l & 15, lk = (l >> 4) * 8;

    for (int k0 = 0; k0 < D_; k0 += 32) {
        __syncthreads();
        GLD16(a0 + k0, asd);
        GLD16(a1 + k0, asd + 2048);
        GLD16(g0 + k0, bsd);
        GLD16(g1 + k0, bsd + 2048);
        __syncthreads();
        short8 af[4], bf[4];
#pragma unroll
        for (int i = 0; i < 4; ++i) af[i] = *(const short8*)&As[(wm + i * 16 + lane15) * 32 + lk];
#pragma unroll
        for (int j = 0; j < 4; ++j) bf[j] = *(const short8*)&Bs[(wn + j * 16 + lane15) * 32 + lk];
#pragma unroll
        for (int i = 0; i < 4; ++i)
#pragma unroll
            for (int j = 0; j < 4; ++j)
                acc[i][j] = __builtin_amdgcn_mfma_f32_16x16x32_bf16(af[i], bf[j], acc[i][j], 0, 0, 0);
    }

    const size_t hbase = ((size_t)bl * E_ + e) * KROW_ * DFF_;
#pragma unroll
    for (int i = 0; i < 4; ++i)
#pragma unroll
        for (int j = 0; j < 4; ++j) {
            const int n = n0 + wn + j * 16 + lane15;
            const float bias = b1[e * DFF_ + n];
#pragma unroll
            for (int r = 0; r < 4; ++r) {
                const int m = m0 + wm + i * 16 + (l >> 4) * 4 + r;
                h[hbase + (size_t)m * DFF_ + n] = f2bf(gelu_tanh(acc[i][j][r] + bias));
            }
        }
}

// ---------------------------------------------------------------------------
// GEMM2: ex[bl,e,j,:] = h[bl,e,j,:] @ w2t[e]^T + b2[e]
// ---------------------------------------------------------------------------
__global__ __launch_bounds__(256) void gemm2_k(
    const unsigned short* __restrict__ h,    // [bchunk,E,KROW,DFF] bf16
    const unsigned short* __restrict__ w2t,  // [E,D,DFF] bf16 (B^T: [N,K])
    const float* __restrict__ b2,            // [E,D] fp32
    unsigned short* __restrict__ ex)         // [bchunk,E,KROW,D] bf16
{
    __shared__ unsigned short As[128 * 32];
    __shared__ unsigned short Bs[128 * 32];
    const int e  = blockIdx.z & 15;
    const int bl = blockIdx.z >> 4;
    const int m0 = blockIdx.x * 128;
    const int n0 = blockIdx.y * 128;
    const int t = threadIdx.x;
    const int w = t >> 6, l = t & 63;
    const int r0 = t >> 2, c0 = (t & 3) * 8;

    const unsigned short* a0 = h + (((size_t)bl * E_ + e) * KROW_ + m0 + r0) * DFF_ + c0;
    const unsigned short* a1 = h + (((size_t)bl * E_ + e) * KROW_ + m0 + 64 + r0) * DFF_ + c0;
    const unsigned short* g0 = w2t + ((size_t)e * D_ + n0 + r0) * DFF_ + c0;
    const unsigned short* g1 = w2t + ((size_t)e * D_ + n0 + 64 + r0) * DFF_ + c0;
    unsigned short* asd = &As[w * 512];
    unsigned short* bsd = &Bs[w * 512];

    floatx4 acc[4][4];
#pragma unroll
    for (int i = 0; i < 4; ++i)
#pragma unroll
        for (int j = 0; j < 4; ++j) acc[i][j] = (floatx4){0.f, 0.f, 0.f, 0.f};

    const int wm = (w >> 1) * 64, wn = (w & 1) * 64;
    const int lane15 = l & 15, lk = (l >> 4) * 8;

    for (int k0 = 0; k0 < DFF_; k0 += 32) {
        __syncthreads();
        GLD16(a0 + k0, asd);
        GLD16(a1 + k0, asd + 2048);
        GLD16(g0 + k0, bsd);
        GLD16(g1 + k0, bsd + 2048);
        __syncthreads();
        short8 af[4], bf[4];
#pragma unroll
        for (int i = 0; i < 4; ++i) af[i] = *(const short8*)&As[(wm + i * 16 + lane15) * 32 + lk];
#pragma unroll
        for (int j = 0; j < 4; ++j) bf[j] = *(const short8*)&Bs[(wn + j * 16 + lane15) * 32 + lk];
#pragma unroll
        for (int i = 0; i < 4; ++i)
#pragma unroll
            for (int j = 0; j < 4; ++j)
                acc[i][j] = __builtin_amdgcn_mfma_f32_16x16x32_bf16(af[i], bf[j], acc[i][j], 0, 0, 0);
    }

    const size_t xbase = ((size_t)bl * E_ + e) * KROW_ * D_;
#pragma unroll
    for (int i = 0; i < 4; ++i)
#pragma unroll
        for (int j = 0; j < 4; ++j) {
            const int n = n0 + wn + j * 16 + lane15;
            const float bias = b2[e * D_ + n];
#pragma unroll
            for (int r = 0; r < 4; ++r) {
                const int m = m0 + wm + i * 16 + (l >> 4) * 4 + r;
                ex[xbase + (size_t)m * D_ + n] = f2bf(acc[i][j][r] + bias);
            }
        }
}

// ---------------------------------------------------------------------------
// Combine: out[b,s,:] = sum_e aff[b,e,s] * ex[bl,e,map[b,s,e],:]   (fp32 out)
// ---------------------------------------------------------------------------
__global__ __launch_bounds__(256) void combine_k(
    const unsigned short* __restrict__ ex, const float* __restrict__ aff,
    const int* __restrict__ map, float* __restrict__ out, int b_base)
{
    const int t = threadIdx.x;
    const int w = t >> 6, l = t & 63;
    const size_t tokl = (size_t)blockIdx.x * 4 + w;   // local token within chunk
    const int bl = (int)(tokl >> 13);
    const int s  = (int)(tokl & (S_ - 1));
    const int b  = b_base + bl;

    int jv = -1; float gv = 0.f;
    if (l < 16) {
        jv = map[((size_t)b * S_ + s) * E_ + l];
        gv = aff[((size_t)b * E_ + l) * S_ + s];
    }
    float acc[8] = {0.f, 0.f, 0.f, 0.f, 0.f, 0.f, 0.f, 0.f};
#pragma unroll
    for (int e = 0; e < E_; ++e) {
        const int je = __shfl(jv, e);
        if (je < 0) continue;
        const float ge = __shfl(gv, e);
        const unsigned short* row = ex + (((size_t)bl * E_ + e) * KROW_ + je) * D_ + l * 8;
        short8 v = *(const short8*)row;
#pragma unroll
        for (int q = 0; q < 8; ++q) acc[q] += ge * bf2f((unsigned short)v[q]);
    }
    float* orow = out + ((size_t)b * S_ + s) * D_ + l * 8;
    float4 o0 = {acc[0], acc[1], acc[2], acc[3]};
    float4 o1 = {acc[4], acc[5], acc[6], acc[7]};
    ((float4*)orow)[0] = o0;
    ((float4*)orow)[1] = o1;
}

// ---------------------------------------------------------------------------
extern "C" void kernel_launch(void* const* d_in, const int* in_sizes, int n_in,
                              void* d_out, int out_size, void* d_ws, size_t ws_size,
                              hipStream_t stream) {
    const float* x  = (const float*)d_in[0];
    const float* gw = (const float*)d_in[1];
    const float* w1 = (const float*)d_in[2];
    const float* b1 = (const float*)d_in[3];
    const float* w2 = (const float*)d_in[4];
    const float* b2 = (const float*)d_in[5];
    float* out = (float*)d_out;
    char* ws = (char*)d_ws;

    size_t off = 0;
    float* aff = (float*)(ws + off);          off += (size_t)B_ * E_ * S_ * 4;       // 4 MB
    int* idxb  = (int*)(ws + off);            off += (size_t)B_ * E_ * KROW_ * 4;    // 0.5 MB
    int* map   = (int*)(ws + off);            off += (size_t)B_ * S_ * E_ * 4;       // 4 MB
    unsigned short* w1t = (unsigned short*)(ws + off); off += (size_t)E_ * DFF_ * D_ * 2; // 8 MB
    unsigned short* w2t = (unsigned short*)(ws + off); off += (size_t)E_ * D_ * DFF_ * 2; // 8 MB
    unsigned short* xb  = (unsigned short*)(ws + off); off += (size_t)B_ * S_ * D_ * 2;   // 64 MB
    const size_t fixed = off;
    const size_t per_b_h  = (size_t)E_ * KROW_ * DFF_ * 2;   // 16 MB
    const size_t per_b_ex = (size_t)E_ * KROW_ * D_ * 2;     // 16 MB
    const size_t per_b = per_b_h + per_b_ex;

    int bchunk = 1;
    if (ws_size > fixed + per_b) {
        size_t m = (ws_size - fixed) / per_b;
        bchunk = (int)(m > (size_t)B_ ? (size_t)B_ : m);
        if (bchunk < 1) bchunk = 1;
    }
    unsigned short* h  = (unsigned short*)(ws + fixed);
    unsigned short* ex = (unsigned short*)(ws + fixed + (size_t)bchunk * per_b_h);

    hipMemsetAsync(map, 0xFF, (size_t)B_ * S_ * E_ * 4, stream);
    cvt_x_k<<<dim3((B_ * S_ * D_ / 4 + 255) / 256), dim3(256), 0, stream>>>(
        x, xb, B_ * S_ * D_ / 4);
    transpose_w_k<<<dim3(16, 16, 32), dim3(32, 8, 1), 0, stream>>>(w1, w2, w1t, w2t);
    router_k<<<dim3((B_ * S_) / 256), dim3(256), 0, stream>>>(x, gw, aff);
    topk_k<<<dim3(B_ * E_), dim3(1024), 0, stream>>>(aff, idxb, map);

    for (int b0 = 0; b0 < B_; b0 += bchunk) {
        const int bc = (b0 + bchunk <= B_) ? bchunk : (B_ - b0);
        gemm1_k<<<dim3(KROW_ / 128, DFF_ / 128, bc * E_), dim3(256), 0, stream>>>(
            xb, w1t, b1, idxb, h, b0);
        gemm2_k<<<dim3(KROW_ / 128, D_ / 128, bc * E_), dim3(256), 0, stream>>>(
            h, w2t, b2, ex);
        combine_k<<<dim3(bc * (S_ / 4)), dim3(256), 0, stream>>>(ex, aff, map, out, b0);
    }
}